// Round 13
// baseline (910.329 us; speedup 1.0000x reference)
//
// GINCombined r13: NT-store CSR scatter; gate fused into mlp block 1 (L2-hot restage)
#include <hip/hip_runtime.h>
#include <math.h>

#define N_NODES 100000
#define N_EDGES 1600000
#define NG      128
#define HD      256
#define PHD     128
#define GFD     32
#define XW      241
#define LN_EPS  1e-5f
#define SLOT    64   // max degree capacity; P(Binomial(1.6M,1e-5) > 64) ~ 1e-18

typedef __attribute__((ext_vector_type(8))) short bf8_t;  // 8 bf16 (4 VGPR)
typedef __attribute__((ext_vector_type(4))) float f4_t;   // 4 f32 acc

static __device__ __forceinline__ float relu_f(float x){ return fmaxf(x, 0.0f); }

static __device__ __forceinline__ unsigned short f2bf_rn(float v) {
    unsigned int u = __float_as_uint(v);
    unsigned int r = (u + 0x7fffu + ((u >> 16) & 1u)) >> 16;
    return (unsigned short)r;
}
static __device__ __forceinline__ float bf2f(unsigned short h) {
    return __uint_as_float((unsigned int)h << 16);
}

// ---------------- h build (fp32 + bf16 mirror) ----------------
__global__ void build_h_kernel(const float* __restrict__ x, const float* __restrict__ emb,
                               float* __restrict__ h, unsigned short* __restrict__ h16)
{
    int node = blockIdx.x;
    int tid  = threadIdx.x;
    const float* xr = x + (size_t)node * XW;
    float v;
    if (tid < 240) {
        v = xr[1 + tid];
    } else {
        int t = (int)xr[0];
        v = emb[t * 16 + (tid - 240)];
    }
    h[(size_t)node * HD + tid] = v;
    h16[(size_t)node * HD + tid] = f2bf_rn(v);
}

// ---------------- single-pass slot-bucketed CSR fill (NT scatter store) ----------------
__global__ void fill_slots_kernel(const int* __restrict__ src, const int* __restrict__ dst,
                                  int* __restrict__ cnt, int* __restrict__ col, int e)
{
    int i = blockIdx.x * blockDim.x + threadIdx.x;
    if (i < e) {
        int d = dst[i];
        int p = atomicAdd(&cnt[d], 1);
        if (p < SLOT) __builtin_nontemporal_store(src[i], &col[(size_t)d * SLOT + p]);
    }
}

// ---------------- aggregate: z = h + sum_neighbors h16 (bf16 gather, 4-way unrolled) ----------------
__global__ __launch_bounds__(256) void aggregate_kernel(
    const float* __restrict__ h, const unsigned short* __restrict__ h16,
    const int* __restrict__ cnt, const int* __restrict__ col,
    float* __restrict__ z, int n)
{
    int node = blockIdx.x * 4 + (threadIdx.x >> 6);
    int lane = threadIdx.x & 63;
    if (node >= n) return;
    const int l4 = lane * 4;
    size_t base = (size_t)node * HD + l4;
    float4 a0 = *(const float4*)&h[base];   // self term exact (fp32)
    float4 a1 = make_float4(0,0,0,0), a2 = make_float4(0,0,0,0), a3 = make_float4(0,0,0,0);
    int deg = cnt[node]; if (deg > SLOT) deg = SLOT;
    const int* cb = col + (size_t)node * SLOT;
    int e = 0;
    for (; e + 4 <= deg; e += 4) {
        int s0 = cb[e], s1 = cb[e+1], s2 = cb[e+2], s3 = cb[e+3];
        ushort4 u0 = *(const ushort4*)&h16[(size_t)s0 * HD + l4];
        ushort4 u1 = *(const ushort4*)&h16[(size_t)s1 * HD + l4];
        ushort4 u2 = *(const ushort4*)&h16[(size_t)s2 * HD + l4];
        ushort4 u3 = *(const ushort4*)&h16[(size_t)s3 * HD + l4];
        a0.x += bf2f(u0.x); a0.y += bf2f(u0.y); a0.z += bf2f(u0.z); a0.w += bf2f(u0.w);
        a1.x += bf2f(u1.x); a1.y += bf2f(u1.y); a1.z += bf2f(u1.z); a1.w += bf2f(u1.w);
        a2.x += bf2f(u2.x); a2.y += bf2f(u2.y); a2.z += bf2f(u2.z); a2.w += bf2f(u2.w);
        a3.x += bf2f(u3.x); a3.y += bf2f(u3.y); a3.z += bf2f(u3.z); a3.w += bf2f(u3.w);
    }
    for (; e < deg; e++) {
        int s = cb[e];
        ushort4 u = *(const ushort4*)&h16[(size_t)s * HD + l4];
        a0.x += bf2f(u.x); a0.y += bf2f(u.y); a0.z += bf2f(u.z); a0.w += bf2f(u.w);
    }
    a0.x += a1.x + a2.x + a3.x;
    a0.y += a1.y + a2.y + a3.y;
    a0.z += a1.z + a2.z + a3.z;
    a0.w += a1.w + a2.w + a3.w;
    *(float4*)&z[base] = a0;
}

// ---------------- merged weight packing (hi only) ----------------
static __device__ __forceinline__ void pack_one(const float* __restrict__ w, short* __restrict__ hi,
                                                int N, int fbase)
{
    int lane = threadIdx.x & 63;
    int f = fbase * 4 + (threadIdx.x >> 6);
    const int KB = 8;            // K=256 always
    int nb = f / KB, kb = f % KB;
    int n = nb * 16 + (lane & 15);
    int k0 = kb * 32 + (lane >> 4) * 8;
    size_t o = (size_t)f * 512 + lane * 8;
    #pragma unroll
    for (int j = 0; j < 8; j++) {
        float v = w[(size_t)(k0 + j) * N + n];
        hi[o + j] = (short)f2bf_rn(v);
    }
}

__global__ __launch_bounds__(256) void pack_all_kernel(
    const float* __restrict__ w0, const float* __restrict__ w1,
    const float* __restrict__ w2, const float* __restrict__ w3,
    const float* __restrict__ w4,
    short* o0h, short* o1h, short* o2h, short* o3h, short* o4h)
{
    int b = blockIdx.x;
    if      (b < 32)  pack_one(w0, o0h, HD,  b);
    else if (b < 64)  pack_one(w1, o1h, HD,  b - 32);
    else if (b < 96)  pack_one(w2, o2h, HD,  b - 64);
    else if (b < 128) pack_one(w3, o3h, HD,  b - 96);
    else              pack_one(w4, o4h, PHD, b - 128);
}

// 32-row split matmul: acc += (Ahi+Alo)@Bh  (bf16 weights, corrected activations)
static __device__ __forceinline__ void mm32(
    f4_t (&acc)[2][4], const char* buf,
    const short* __restrict__ Bh,
    int wc, int cb, int kg, int lane)
{
    bf8_t bcur[4], bnxt[4];
    #pragma unroll
    for (int ni = 0; ni < 4; ni++)
        bcur[ni] = *(const bf8_t*)&Bh[((size_t)((wc*4+ni)*8))*512 + lane*8];
    for (int kb = 0; kb < 8; kb++) {
        if (kb < 7) {
            #pragma unroll
            for (int ni = 0; ni < 4; ni++)
                bnxt[ni] = *(const bf8_t*)&Bh[((size_t)((wc*4+ni)*8 + kb+1))*512 + lane*8];
        }
        bf8_t ahi[2], alo[2];
        #pragma unroll
        for (int mi = 0; mi < 2; mi++) {
            int row = mi*16 + cb;
            int byte = (row*512 + kb*64 + kg*16) ^ ((row & 7) << 4);
            ahi[mi] = *(const bf8_t*)(buf + byte);
            alo[mi] = *(const bf8_t*)(buf + 16384 + byte);
        }
        #pragma unroll
        for (int mi = 0; mi < 2; mi++)
            #pragma unroll
            for (int ni = 0; ni < 4; ni++)
                acc[mi][ni] = __builtin_amdgcn_mfma_f32_16x16x32_bf16(ahi[mi], bcur[ni], acc[mi][ni], 0, 0, 0);
        #pragma unroll
        for (int mi = 0; mi < 2; mi++)
            #pragma unroll
            for (int ni = 0; ni < 4; ni++)
                acc[mi][ni] = __builtin_amdgcn_mfma_f32_16x16x32_bf16(alo[mi], bcur[ni], acc[mi][ni], 0, 0, 0);
        #pragma unroll
        for (int ni = 0; ni < 4; ni++) bcur[ni] = bnxt[ni];
    }
}

// ---------------- fused MLP + LN + residual (+ optional gate) ----------------
// 32 rows/block, 32KB LDS, 4 blocks/CU
__global__ __launch_bounds__(256, 4) void mlp_mfma_kernel(
    float* __restrict__ h, unsigned short* __restrict__ h16, const float* __restrict__ z,
    const short* __restrict__ w1h, const float* __restrict__ b1,
    const short* __restrict__ w2h, const float* __restrict__ b2,
    const float* __restrict__ lng, const float* __restrict__ lnb,
    const short* __restrict__ g1h, const float* __restrict__ gb1,
    const float* __restrict__ gw2, const float* __restrict__ gb2,
    float* __restrict__ gate, int do_gate)
{
    __shared__ char buf[32768];
    const int tid  = threadIdx.x;
    const int lane = tid & 63;
    const int wv   = tid >> 6;      // 0..3 (column group)
    const int cb   = lane & 15;
    const int kg   = lane >> 4;
    const long row0 = (long)blockIdx.x * 32;

    // ---- stage z tile [32][256]: split hi/lo, swizzled (8 rows per wave) ----
    for (int rr = 0; rr < 8; rr++) {
        int row = wv * 8 + rr;
        long grow = row0 + row;
        float4 v = make_float4(0.f, 0.f, 0.f, 0.f);
        if (grow < N_NODES) v = *(const float4*)&z[grow * HD + lane * 4];
        ushort4 hi4, lo4;
        unsigned short hb;
        hb = f2bf_rn(v.x); hi4.x = hb; lo4.x = f2bf_rn(v.x - bf2f(hb));
        hb = f2bf_rn(v.y); hi4.y = hb; lo4.y = f2bf_rn(v.y - bf2f(hb));
        hb = f2bf_rn(v.z); hi4.z = hb; lo4.z = f2bf_rn(v.z - bf2f(hb));
        hb = f2bf_rn(v.w); hi4.w = hb; lo4.w = f2bf_rn(v.w - bf2f(hb));
        int byte = (row * 512 + lane * 8) ^ ((row & 7) << 4);
        *(ushort4*)(buf + byte)         = hi4;
        *(ushort4*)(buf + 16384 + byte) = lo4;
    }
    __syncthreads();

    f4_t acc[2][4];
    const f4_t zero4 = {0.f, 0.f, 0.f, 0.f};
    #pragma unroll
    for (int mi = 0; mi < 2; mi++)
        #pragma unroll
        for (int ni = 0; ni < 4; ni++) acc[mi][ni] = zero4;

    mm32(acc, buf, w1h, wv, cb, kg, lane);
    __syncthreads();

    // ---- t = relu(acc + b1) -> hi/lo swizzled back into buf ----
    {
        float bias1[4];
        #pragma unroll
        for (int ni = 0; ni < 4; ni++) bias1[ni] = b1[wv * 64 + ni * 16 + cb];
        #pragma unroll
        for (int mi = 0; mi < 2; mi++) {
            #pragma unroll
            for (int ni = 0; ni < 4; ni++) {
                int colx2 = (wv * 64 + ni * 16 + cb) * 2;
                #pragma unroll
                for (int j = 0; j < 4; j++) {
                    float t = relu_f(acc[mi][ni][j] + bias1[ni]);
                    int row = mi * 16 + kg * 4 + j;
                    unsigned short hb = f2bf_rn(t);
                    unsigned short lb = f2bf_rn(t - bf2f(hb));
                    int byte = (row * 512 + colx2) ^ ((row & 7) << 4);
                    *(short*)(buf + byte)         = (short)hb;
                    *(short*)(buf + 16384 + byte) = (short)lb;
                }
            }
        }
    }
    __syncthreads();

    #pragma unroll
    for (int mi = 0; mi < 2; mi++)
        #pragma unroll
        for (int ni = 0; ni < 4; ni++) acc[mi][ni] = zero4;

    mm32(acc, buf, w2h, wv, cb, kg, lane);
    __syncthreads();

    // ---- z2 = acc + b2 -> f32 [32][256] over whole buf (64B-chunk swizzle) ----
    {
        float bias2[4];
        #pragma unroll
        for (int ni = 0; ni < 4; ni++) bias2[ni] = b2[wv * 64 + ni * 16 + cb];
        #pragma unroll
        for (int mi = 0; mi < 2; mi++) {
            #pragma unroll
            for (int ni = 0; ni < 4; ni++) {
                int col = wv * 64 + ni * 16 + cb;
                #pragma unroll
                for (int j = 0; j < 4; j++) {
                    int row = mi * 16 + kg * 4 + j;
                    int byte = (row * 1024 + col * 4) ^ (((row >> 2) & 3) << 6);
                    *(float*)(buf + byte) = acc[mi][ni][j] + bias2[ni];
                }
            }
        }
    }
    __syncthreads();

    // ---- LN + relu + residual; write h fp32 + h16 mirror (8 rows per wave) ----
    {
        const float4 gv = *(const float4*)&lng[lane * 4];
        const float4 bv = *(const float4*)&lnb[lane * 4];
        for (int rr = 0; rr < 8; rr++) {
            int row = wv * 8 + rr;
            long grow = row0 + row;
            if (grow >= N_NODES) break;
            int byte = (row * 1024 + lane * 16) ^ (((row >> 2) & 3) << 6);
            float4 v = *(const float4*)(buf + byte);
            float s = v.x + v.y + v.z + v.w;
            float q = v.x * v.x + v.y * v.y + v.z * v.z + v.w * v.w;
            #pragma unroll
            for (int off = 32; off > 0; off >>= 1) {
                s += __shfl_xor(s, off, 64);
                q += __shfl_xor(q, off, 64);
            }
            float mu = s * (1.0f / 256.0f);
            float var = q * (1.0f / 256.0f) - mu * mu;
            float rstd = rsqrtf(var + LN_EPS);
            size_t gi = (size_t)grow * HD + lane * 4;
            float4 hv = *(float4*)&h[gi];
            hv.x += relu_f((v.x - mu) * rstd * gv.x + bv.x);
            hv.y += relu_f((v.y - mu) * rstd * gv.y + bv.y);
            hv.z += relu_f((v.z - mu) * rstd * gv.z + bv.z);
            hv.w += relu_f((v.w - mu) * rstd * gv.w + bv.w);
            *(float4*)&h[gi] = hv;
            ushort4 m16;
            m16.x = f2bf_rn(hv.x); m16.y = f2bf_rn(hv.y);
            m16.z = f2bf_rn(hv.z); m16.w = f2bf_rn(hv.w);
            *(ushort4*)&h16[gi] = m16;
        }
    }

    if (!do_gate) return;

    // ================= fused gate: gate = relu(h@gw1+gb1)@gw2 + gb2 =================
    __syncthreads();   // all z2 reads done; buf reusable

    // ---- restage h tile (L2-hot: just written by this block) hi/lo swizzled ----
    for (int rr = 0; rr < 8; rr++) {
        int row = wv * 8 + rr;
        long grow = row0 + row;
        float4 v = make_float4(0.f, 0.f, 0.f, 0.f);
        if (grow < N_NODES) v = *(const float4*)&h[grow * HD + lane * 4];
        ushort4 hi4, lo4;
        unsigned short hb;
        hb = f2bf_rn(v.x); hi4.x = hb; lo4.x = f2bf_rn(v.x - bf2f(hb));
        hb = f2bf_rn(v.y); hi4.y = hb; lo4.y = f2bf_rn(v.y - bf2f(hb));
        hb = f2bf_rn(v.z); hi4.z = hb; lo4.z = f2bf_rn(v.z - bf2f(hb));
        hb = f2bf_rn(v.w); hi4.w = hb; lo4.w = f2bf_rn(v.w - bf2f(hb));
        int byte = (row * 512 + lane * 8) ^ ((row & 7) << 4);
        *(ushort4*)(buf + byte)         = hi4;
        *(ushort4*)(buf + 16384 + byte) = lo4;
    }
    __syncthreads();

    // ---- gate matmul1: [32][256] @ [256][128], wave covers cols wv*32..wv*32+31 ----
    f4_t gacc[2][2];
    #pragma unroll
    for (int mi = 0; mi < 2; mi++) { gacc[mi][0] = zero4; gacc[mi][1] = zero4; }
    #pragma unroll
    for (int pass = 0; pass < 2; pass++) {
        const char* Abase = (pass == 1) ? (buf + 16384) : buf;
        for (int kb = 0; kb < 8; kb++) {
            bf8_t a[2], b[2];
            #pragma unroll
            for (int mi = 0; mi < 2; mi++) {
                int row = mi * 16 + cb;
                int byte = (row * 512 + kb * 64 + kg * 16) ^ ((row & 7) << 4);
                a[mi] = *(const bf8_t*)(Abase + byte);
            }
            #pragma unroll
            for (int ni = 0; ni < 2; ni++) {
                int nb = wv * 2 + ni;
                b[ni] = *(const bf8_t*)&g1h[(size_t)(nb * 8 + kb) * 512 + lane * 8];
            }
            #pragma unroll
            for (int mi = 0; mi < 2; mi++)
                #pragma unroll
                for (int ni = 0; ni < 2; ni++)
                    gacc[mi][ni] = __builtin_amdgcn_mfma_f32_16x16x32_bf16(a[mi], b[ni], gacc[mi][ni], 0, 0, 0);
        }
    }
    __syncthreads();   // mm reads of buf done before G1 overwrite

    // ---- G1 = relu(gacc + gb1) -> f32 [32][128] in buf ----
    {
        float* G1 = (float*)buf;
        float bias1[2];
        bias1[0] = gb1[wv * 32 + cb];
        bias1[1] = gb1[wv * 32 + 16 + cb];
        #pragma unroll
        for (int mi = 0; mi < 2; mi++) {
            #pragma unroll
            for (int ni = 0; ni < 2; ni++) {
                int colv = wv * 32 + ni * 16 + cb;
                #pragma unroll
                for (int j = 0; j < 4; j++) {
                    int row = mi * 16 + kg * 4 + j;
                    G1[row * PHD + colv] = relu_f(gacc[mi][ni][j] + bias1[ni]);
                }
            }
        }
    }
    __syncthreads();

    // ---- stage 2: dot with gw2 over 128 (8 rows per wave) ----
    {
        const float* G1 = (const float*)buf;
        float2 wv2 = *(const float2*)&gw2[lane * 2];
        float b2v = gb2[0];
        for (int rr = 0; rr < 8; rr++) {
            int row = wv * 8 + rr;
            long grow = row0 + row;
            if (grow >= N_NODES) break;
            float2 t2 = *(const float2*)&G1[row * PHD + lane * 2];
            float p = t2.x * wv2.x + t2.y * wv2.y;
            #pragma unroll
            for (int off = 32; off > 0; off >>= 1) p += __shfl_xor(p, off, 64);
            if (lane == 0) gate[grow] = p + b2v;
        }
    }
}

// ---------------- graph offsets ----------------
__global__ void goff_kernel(const int* __restrict__ batch, int* __restrict__ goff, int n)
{
    int t = threadIdx.x;
    if (t > NG) return;
    int lo = 0, hi = n;
    while (lo < hi) {
        int mid = (lo + hi) >> 1;
        if (batch[mid] < t) lo = mid + 1; else hi = mid;
    }
    goff[t] = lo;
}

// ---------------- softmax-weighted pooling (4 blocks per graph, atomic accumulate) ----------------
__global__ __launch_bounds__(256) void pool_kernel(
    const float* __restrict__ h, const float* __restrict__ gate,
    const int* __restrict__ goff, float* __restrict__ pooled)
{
    __shared__ float red[256];
    __shared__ float m_sh, s_sh;
    int g = blockIdx.x >> 2, q = blockIdx.x & 3;
    int tid = threadIdx.x;
    int beg = goff[g], end = goff[g + 1];
    if (beg >= end) return;   // pooled pre-zeroed

    float lm = -3.4e38f;
    for (int i = beg + tid; i < end; i += 256) lm = fmaxf(lm, gate[i]);
    red[tid] = lm; __syncthreads();
    for (int off = 128; off > 0; off >>= 1) {
        if (tid < off) red[tid] = fmaxf(red[tid], red[tid + off]);
        __syncthreads();
    }
    if (tid == 0) m_sh = red[0];
    __syncthreads();
    float m = m_sh;

    float ls = 0.0f;
    for (int i = beg + tid; i < end; i += 256) ls += expf(gate[i] - m);
    __syncthreads();
    red[tid] = ls; __syncthreads();
    for (int off = 128; off > 0; off >>= 1) {
        if (tid < off) red[tid] += red[tid + off];
        __syncthreads();
    }
    if (tid == 0) s_sh = red[0];
    __syncthreads();
    float inv_s = 1.0f / s_sh;

    float acc = 0.0f;
    for (int i = beg + q; i < end; i += 4) {
        float a = expf(gate[i] - m);
        acc += a * h[(size_t)i * HD + tid];
    }
    atomicAdd(&pooled[(size_t)g * HD + tid], acc * inv_s);
}

// ---------------- classifier ----------------
__global__ __launch_bounds__(128) void cls_kernel(
    const float* __restrict__ pooled, const float* __restrict__ gf,
    const float* __restrict__ w1, const float* __restrict__ b1,
    const float* __restrict__ w2, const float* __restrict__ b2,
    float* __restrict__ out)
{
    __shared__ float r0[128], r1[128];
    int g = blockIdx.x, c = threadIdx.x;
    float acc = b1[c];
    const float* pr = pooled + (size_t)g * HD;
    for (int k = 0; k < HD; k++) acc += pr[k] * w1[k * PHD + c];
    const float* gr = gf + g * GFD;
    for (int k = 0; k < GFD; k++) acc += gr[k] * w1[(HD + k) * PHD + c];
    float t = relu_f(acc);
    r0[c] = t * w2[c * 2 + 0];
    r1[c] = t * w2[c * 2 + 1];
    __syncthreads();
    for (int off = 64; off > 0; off >>= 1) {
        if (c < off) { r0[c] += r0[c + off]; r1[c] += r1[c + off]; }
        __syncthreads();
    }
    if (c == 0) {
        out[g * 2 + 0] = r0[0] + b2[0];
        out[g * 2 + 1] = r1[0] + b2[1];
    }
}

extern "C" void kernel_launch(void* const* d_in, const int* in_sizes, int n_in,
                              void* d_out, int out_size, void* d_ws, size_t ws_size,
                              hipStream_t stream)
{
    const float* x    = (const float*)d_in[0];
    const int*   ei   = (const int*)d_in[1];
    const int*   bat  = (const int*)d_in[2];
    const float* gf   = (const float*)d_in[3];
    const float* emb  = (const float*)d_in[4];
    const float* l0w1 = (const float*)d_in[5];
    const float* l0b1 = (const float*)d_in[6];
    const float* l0w2 = (const float*)d_in[7];
    const float* l0b2 = (const float*)d_in[8];
    const float* ln0g = (const float*)d_in[9];
    const float* ln0b = (const float*)d_in[10];
    const float* l1w1 = (const float*)d_in[11];
    const float* l1b1 = (const float*)d_in[12];
    const float* l1w2 = (const float*)d_in[13];
    const float* l1b2 = (const float*)d_in[14];
    const float* ln1g = (const float*)d_in[15];
    const float* ln1b = (const float*)d_in[16];
    const float* gw1  = (const float*)d_in[17];
    const float* gb1  = (const float*)d_in[18];
    const float* gw2  = (const float*)d_in[19];
    const float* gb2  = (const float*)d_in[20];
    const float* cw1  = (const float*)d_in[21];
    const float* cb1  = (const float*)d_in[22];
    const float* cw2  = (const float*)d_in[23];
    const float* cb2  = (const float*)d_in[24];

    char* ws = (char*)d_ws;
    size_t off = 0;
    auto alloc = [&](size_t bytes) {
        void* p = ws + off;
        off += (bytes + 255) & ~(size_t)255;
        return p;
    };
    float* h      = (float*)alloc((size_t)N_NODES * HD * 4);
    unsigned short* h16 = (unsigned short*)alloc((size_t)N_NODES * HD * 2);
    float* z      = (float*)alloc((size_t)N_NODES * HD * 4);
    float* gate   = (float*)alloc((size_t)N_NODES * 4);
    int*   cnt    = (int*)alloc((size_t)N_NODES * 4);
    int*   col    = (int*)alloc((size_t)N_NODES * SLOT * 4);
    int*   goff   = (int*)alloc((NG + 1) * 4);
    float* pooled = (float*)alloc((size_t)NG * HD * 4);
    short* p_l0w1h = (short*)alloc((size_t)HD * HD * 2);
    short* p_l0w2h = (short*)alloc((size_t)HD * HD * 2);
    short* p_l1w1h = (short*)alloc((size_t)HD * HD * 2);
    short* p_l1w2h = (short*)alloc((size_t)HD * HD * 2);
    short* p_gw1h  = (short*)alloc((size_t)HD * PHD * 2);

    const int* src = ei;
    const int* dst = ei + N_EDGES;

    build_h_kernel<<<N_NODES, 256, 0, stream>>>(x, emb, h, h16);

    // slot-bucketed CSR: one atomic pass, no count/scan; NT scatter store
    hipMemsetAsync(cnt, 0, (size_t)N_NODES * 4, stream);
    fill_slots_kernel<<<(N_EDGES + 255) / 256, 256, 0, stream>>>(src, dst, cnt, col, N_EDGES);

    pack_all_kernel<<<144, 256, 0, stream>>>(l0w1, l0w2, l1w1, l1w2, gw1,
                                             p_l0w1h, p_l0w2h, p_l1w1h, p_l1w2h, p_gw1h);

    const int mlp_grid = (N_NODES + 31) / 32;   // 3125

    // GIN block 0
    aggregate_kernel<<<N_NODES / 4, 256, 0, stream>>>(h, h16, cnt, col, z, N_NODES);
    mlp_mfma_kernel<<<mlp_grid, 256, 0, stream>>>(h, h16, z, p_l0w1h, l0b1,
                                                  p_l0w2h, l0b2, ln0g, ln0b,
                                                  p_gw1h, gb1, gw2, gb2, gate, 0);
    // GIN block 1 + fused gate
    aggregate_kernel<<<N_NODES / 4, 256, 0, stream>>>(h, h16, cnt, col, z, N_NODES);
    mlp_mfma_kernel<<<mlp_grid, 256, 0, stream>>>(h, h16, z, p_l1w1h, l1b1,
                                                  p_l1w2h, l1b2, ln1g, ln1b,
                                                  p_gw1h, gb1, gw2, gb2, gate, 1);

    goff_kernel<<<1, 256, 0, stream>>>(bat, goff, N_NODES);
    hipMemsetAsync(pooled, 0, (size_t)NG * HD * 4, stream);
    pool_kernel<<<NG * 4, 256, 0, stream>>>(h, gate, goff, pooled);
    cls_kernel<<<NG, 128, 0, stream>>>(pooled, gf, cw1, cb1, cw2, cb2, (float*)d_out);
}

// Round 14
// 769.677 us; speedup vs baseline: 1.1827x; 1.1827x over previous
//
// GINCombined r14: revert r13 (gate refission, plain CSR store); fuse aggregate into MLP via h16 ping-pong (z eliminated)
#include <hip/hip_runtime.h>
#include <math.h>

#define N_NODES 100000
#define N_EDGES 1600000
#define NG      128
#define HD      256
#define PHD     128
#define GFD     32
#define XW      241
#define LN_EPS  1e-5f
#define SLOT    64   // max degree capacity; P(Binomial(1.6M,1e-5) > 64) ~ 1e-18

typedef __attribute__((ext_vector_type(8))) short bf8_t;  // 8 bf16 (4 VGPR)
typedef __attribute__((ext_vector_type(4))) float f4_t;   // 4 f32 acc

static __device__ __forceinline__ float relu_f(float x){ return fmaxf(x, 0.0f); }

static __device__ __forceinline__ unsigned short f2bf_rn(float v) {
    unsigned int u = __float_as_uint(v);
    unsigned int r = (u + 0x7fffu + ((u >> 16) & 1u)) >> 16;
    return (unsigned short)r;
}
static __device__ __forceinline__ float bf2f(unsigned short h) {
    return __uint_as_float((unsigned int)h << 16);
}

// ---------------- h build (fp32 + bf16 mirror) ----------------
__global__ void build_h_kernel(const float* __restrict__ x, const float* __restrict__ emb,
                               float* __restrict__ h, unsigned short* __restrict__ h16)
{
    int node = blockIdx.x;
    int tid  = threadIdx.x;
    const float* xr = x + (size_t)node * XW;
    float v;
    if (tid < 240) {
        v = xr[1 + tid];
    } else {
        int t = (int)xr[0];
        v = emb[t * 16 + (tid - 240)];
    }
    h[(size_t)node * HD + tid] = v;
    h16[(size_t)node * HD + tid] = f2bf_rn(v);
}

// ---------------- single-pass slot-bucketed CSR fill ----------------
__global__ void fill_slots_kernel(const int* __restrict__ src, const int* __restrict__ dst,
                                  int* __restrict__ cnt, int* __restrict__ col, int e)
{
    int i = blockIdx.x * blockDim.x + threadIdx.x;
    if (i < e) {
        int d = dst[i];
        int p = atomicAdd(&cnt[d], 1);
        if (p < SLOT) col[(size_t)d * SLOT + p] = src[i];
    }
}

// ---------------- merged weight packing (hi only) ----------------
static __device__ __forceinline__ void pack_one(const float* __restrict__ w, short* __restrict__ hi,
                                                int N, int fbase)
{
    int lane = threadIdx.x & 63;
    int f = fbase * 4 + (threadIdx.x >> 6);
    const int KB = 8;            // K=256 always
    int nb = f / KB, kb = f % KB;
    int n = nb * 16 + (lane & 15);
    int k0 = kb * 32 + (lane >> 4) * 8;
    size_t o = (size_t)f * 512 + lane * 8;
    #pragma unroll
    for (int j = 0; j < 8; j++) {
        float v = w[(size_t)(k0 + j) * N + n];
        hi[o + j] = (short)f2bf_rn(v);
    }
}

__global__ __launch_bounds__(256) void pack_all_kernel(
    const float* __restrict__ w0, const float* __restrict__ w1,
    const float* __restrict__ w2, const float* __restrict__ w3,
    const float* __restrict__ w4,
    short* o0h, short* o1h, short* o2h, short* o3h, short* o4h)
{
    int b = blockIdx.x;
    if      (b < 32)  pack_one(w0, o0h, HD,  b);
    else if (b < 64)  pack_one(w1, o1h, HD,  b - 32);
    else if (b < 96)  pack_one(w2, o2h, HD,  b - 64);
    else if (b < 128) pack_one(w3, o3h, HD,  b - 96);
    else              pack_one(w4, o4h, PHD, b - 128);
}

// 32-row split matmul: acc += (Ahi+Alo)@Bh  (bf16 weights, corrected activations)
static __device__ __forceinline__ void mm32(
    f4_t (&acc)[2][4], const char* buf,
    const short* __restrict__ Bh,
    int wc, int cb, int kg, int lane)
{
    bf8_t bcur[4], bnxt[4];
    #pragma unroll
    for (int ni = 0; ni < 4; ni++)
        bcur[ni] = *(const bf8_t*)&Bh[((size_t)((wc*4+ni)*8))*512 + lane*8];
    for (int kb = 0; kb < 8; kb++) {
        if (kb < 7) {
            #pragma unroll
            for (int ni = 0; ni < 4; ni++)
                bnxt[ni] = *(const bf8_t*)&Bh[((size_t)((wc*4+ni)*8 + kb+1))*512 + lane*8];
        }
        bf8_t ahi[2], alo[2];
        #pragma unroll
        for (int mi = 0; mi < 2; mi++) {
            int row = mi*16 + cb;
            int byte = (row*512 + kb*64 + kg*16) ^ ((row & 7) << 4);
            ahi[mi] = *(const bf8_t*)(buf + byte);
            alo[mi] = *(const bf8_t*)(buf + 16384 + byte);
        }
        #pragma unroll
        for (int mi = 0; mi < 2; mi++)
            #pragma unroll
            for (int ni = 0; ni < 4; ni++)
                acc[mi][ni] = __builtin_amdgcn_mfma_f32_16x16x32_bf16(ahi[mi], bcur[ni], acc[mi][ni], 0, 0, 0);
        #pragma unroll
        for (int mi = 0; mi < 2; mi++)
            #pragma unroll
            for (int ni = 0; ni < 4; ni++)
                acc[mi][ni] = __builtin_amdgcn_mfma_f32_16x16x32_bf16(alo[mi], bcur[ni], acc[mi][ni], 0, 0, 0);
        #pragma unroll
        for (int ni = 0; ni < 4; ni++) bcur[ni] = bnxt[ni];
    }
}

// ---------------- fused GIN layer: gather + MLP + LN + residual ----------------
// z never materialized: per-row z = h(fp32) + sum_nbr h16_in; writes h (fp32) and h16_out.
// h16 ping-pong across layers makes the in-kernel gather race-free.
// 32 rows/block, 32KB LDS, 4 blocks/CU.
__global__ __launch_bounds__(256, 4) void gin_layer_kernel(
    float* __restrict__ h, const unsigned short* __restrict__ h16i,
    unsigned short* __restrict__ h16o,
    const int* __restrict__ cnt, const int* __restrict__ col,
    const short* __restrict__ w1h, const float* __restrict__ b1,
    const short* __restrict__ w2h, const float* __restrict__ b2,
    const float* __restrict__ lng, const float* __restrict__ lnb)
{
    __shared__ char buf[32768];
    const int tid  = threadIdx.x;
    const int lane = tid & 63;
    const int wv   = tid >> 6;      // 0..3 (column group)
    const int cb   = lane & 15;
    const int kg   = lane >> 4;
    const int l4   = lane * 4;
    const long row0 = (long)blockIdx.x * 32;

    // ---- gather+stage z tile [32][256] (grid covers N exactly: 3125*32=100000) ----
    for (int rr = 0; rr < 8; rr++) {
        int row = wv * 8 + rr;
        long grow = row0 + row;
        float4 a0 = *(const float4*)&h[grow * HD + l4];   // self term exact (fp32)
        float4 a1 = make_float4(0,0,0,0), a2 = make_float4(0,0,0,0), a3 = make_float4(0,0,0,0);
        int deg = cnt[grow]; if (deg > SLOT) deg = SLOT;
        const int* cb4 = col + (size_t)grow * SLOT;
        int e = 0;
        for (; e + 4 <= deg; e += 4) {
            int s0 = cb4[e], s1 = cb4[e+1], s2 = cb4[e+2], s3 = cb4[e+3];
            ushort4 u0 = *(const ushort4*)&h16i[(size_t)s0 * HD + l4];
            ushort4 u1 = *(const ushort4*)&h16i[(size_t)s1 * HD + l4];
            ushort4 u2 = *(const ushort4*)&h16i[(size_t)s2 * HD + l4];
            ushort4 u3 = *(const ushort4*)&h16i[(size_t)s3 * HD + l4];
            a0.x += bf2f(u0.x); a0.y += bf2f(u0.y); a0.z += bf2f(u0.z); a0.w += bf2f(u0.w);
            a1.x += bf2f(u1.x); a1.y += bf2f(u1.y); a1.z += bf2f(u1.z); a1.w += bf2f(u1.w);
            a2.x += bf2f(u2.x); a2.y += bf2f(u2.y); a2.z += bf2f(u2.z); a2.w += bf2f(u2.w);
            a3.x += bf2f(u3.x); a3.y += bf2f(u3.y); a3.z += bf2f(u3.z); a3.w += bf2f(u3.w);
        }
        for (; e < deg; e++) {
            int s = cb4[e];
            ushort4 u = *(const ushort4*)&h16i[(size_t)s * HD + l4];
            a0.x += bf2f(u.x); a0.y += bf2f(u.y); a0.z += bf2f(u.z); a0.w += bf2f(u.w);
        }
        a0.x += a1.x + a2.x + a3.x;
        a0.y += a1.y + a2.y + a3.y;
        a0.z += a1.z + a2.z + a3.z;
        a0.w += a1.w + a2.w + a3.w;
        // split hi/lo -> LDS swizzled
        ushort4 hi4, lo4;
        unsigned short hb;
        hb = f2bf_rn(a0.x); hi4.x = hb; lo4.x = f2bf_rn(a0.x - bf2f(hb));
        hb = f2bf_rn(a0.y); hi4.y = hb; lo4.y = f2bf_rn(a0.y - bf2f(hb));
        hb = f2bf_rn(a0.z); hi4.z = hb; lo4.z = f2bf_rn(a0.z - bf2f(hb));
        hb = f2bf_rn(a0.w); hi4.w = hb; lo4.w = f2bf_rn(a0.w - bf2f(hb));
        int byte = (row * 512 + lane * 8) ^ ((row & 7) << 4);
        *(ushort4*)(buf + byte)         = hi4;
        *(ushort4*)(buf + 16384 + byte) = lo4;
    }
    __syncthreads();

    f4_t acc[2][4];
    const f4_t zero4 = {0.f, 0.f, 0.f, 0.f};
    #pragma unroll
    for (int mi = 0; mi < 2; mi++)
        #pragma unroll
        for (int ni = 0; ni < 4; ni++) acc[mi][ni] = zero4;

    mm32(acc, buf, w1h, wv, cb, kg, lane);
    __syncthreads();

    // ---- t = relu(acc + b1) -> hi/lo swizzled back into buf ----
    {
        float bias1[4];
        #pragma unroll
        for (int ni = 0; ni < 4; ni++) bias1[ni] = b1[wv * 64 + ni * 16 + cb];
        #pragma unroll
        for (int mi = 0; mi < 2; mi++) {
            #pragma unroll
            for (int ni = 0; ni < 4; ni++) {
                int colx2 = (wv * 64 + ni * 16 + cb) * 2;
                #pragma unroll
                for (int j = 0; j < 4; j++) {
                    float t = relu_f(acc[mi][ni][j] + bias1[ni]);
                    int row = mi * 16 + kg * 4 + j;
                    unsigned short hb = f2bf_rn(t);
                    unsigned short lb = f2bf_rn(t - bf2f(hb));
                    int byte = (row * 512 + colx2) ^ ((row & 7) << 4);
                    *(short*)(buf + byte)         = (short)hb;
                    *(short*)(buf + 16384 + byte) = (short)lb;
                }
            }
        }
    }
    __syncthreads();

    #pragma unroll
    for (int mi = 0; mi < 2; mi++)
        #pragma unroll
        for (int ni = 0; ni < 4; ni++) acc[mi][ni] = zero4;

    mm32(acc, buf, w2h, wv, cb, kg, lane);
    __syncthreads();

    // ---- z2 = acc + b2 -> f32 [32][256] over whole buf (64B-chunk swizzle) ----
    {
        float bias2[4];
        #pragma unroll
        for (int ni = 0; ni < 4; ni++) bias2[ni] = b2[wv * 64 + ni * 16 + cb];
        #pragma unroll
        for (int mi = 0; mi < 2; mi++) {
            #pragma unroll
            for (int ni = 0; ni < 4; ni++) {
                int col2 = wv * 64 + ni * 16 + cb;
                #pragma unroll
                for (int j = 0; j < 4; j++) {
                    int row = mi * 16 + kg * 4 + j;
                    int byte = (row * 1024 + col2 * 4) ^ (((row >> 2) & 3) << 6);
                    *(float*)(buf + byte) = acc[mi][ni][j] + bias2[ni];
                }
            }
        }
    }
    __syncthreads();

    // ---- LN + relu + residual; write h fp32 + h16_out mirror (8 rows per wave) ----
    {
        const float4 gv = *(const float4*)&lng[l4];
        const float4 bv = *(const float4*)&lnb[l4];
        for (int rr = 0; rr < 8; rr++) {
            int row = wv * 8 + rr;
            long grow = row0 + row;
            int byte = (row * 1024 + lane * 16) ^ (((row >> 2) & 3) << 6);
            float4 v = *(const float4*)(buf + byte);
            float s = v.x + v.y + v.z + v.w;
            float q = v.x * v.x + v.y * v.y + v.z * v.z + v.w * v.w;
            #pragma unroll
            for (int off = 32; off > 0; off >>= 1) {
                s += __shfl_xor(s, off, 64);
                q += __shfl_xor(q, off, 64);
            }
            float mu = s * (1.0f / 256.0f);
            float var = q * (1.0f / 256.0f) - mu * mu;
            float rstd = rsqrtf(var + LN_EPS);
            size_t gi = (size_t)grow * HD + l4;
            float4 hv = *(float4*)&h[gi];
            hv.x += relu_f((v.x - mu) * rstd * gv.x + bv.x);
            hv.y += relu_f((v.y - mu) * rstd * gv.y + bv.y);
            hv.z += relu_f((v.z - mu) * rstd * gv.z + bv.z);
            hv.w += relu_f((v.w - mu) * rstd * gv.w + bv.w);
            *(float4*)&h[gi] = hv;
            ushort4 m16;
            m16.x = f2bf_rn(hv.x); m16.y = f2bf_rn(hv.y);
            m16.z = f2bf_rn(hv.z); m16.w = f2bf_rn(hv.w);
            *(ushort4*)&h16o[gi] = m16;
        }
    }
}

// ---------------- gate via split-bf16 MFMA (64 rows/block, 2-pass) ----------------
__global__ __launch_bounds__(256, 2) void gate_mfma_kernel(
    const float* __restrict__ h,
    const short* __restrict__ g1h, const float* __restrict__ gb1,
    const float* __restrict__ gw2, const float* __restrict__ gb2,
    float* __restrict__ gate)
{
    __shared__ char buf[65536];
    const int tid  = threadIdx.x;
    const int lane = tid & 63;
    const int wv   = tid >> 6;
    const int cb   = lane & 15;
    const int kg   = lane >> 4;
    const long row0 = (long)blockIdx.x * 64;

    for (int rr = 0; rr < 16; rr++) {
        int row = wv * 16 + rr;
        long grow = row0 + row;
        float4 v = make_float4(0.f, 0.f, 0.f, 0.f);
        if (grow < N_NODES) v = *(const float4*)&h[grow * HD + lane * 4];
        ushort4 hi4, lo4;
        unsigned short hb;
        hb = f2bf_rn(v.x); hi4.x = hb; lo4.x = f2bf_rn(v.x - bf2f(hb));
        hb = f2bf_rn(v.y); hi4.y = hb; lo4.y = f2bf_rn(v.y - bf2f(hb));
        hb = f2bf_rn(v.z); hi4.z = hb; lo4.z = f2bf_rn(v.z - bf2f(hb));
        hb = f2bf_rn(v.w); hi4.w = hb; lo4.w = f2bf_rn(v.w - bf2f(hb));
        int byte = (row * 512 + lane * 8) ^ ((row & 7) << 4);
        *(ushort4*)(buf + byte)         = hi4;
        *(ushort4*)(buf + 32768 + byte) = lo4;
    }
    __syncthreads();

    f4_t acc[4][2];
    const f4_t zero4 = {0.f, 0.f, 0.f, 0.f};
    #pragma unroll
    for (int mi = 0; mi < 4; mi++) { acc[mi][0] = zero4; acc[mi][1] = zero4; }

    #pragma unroll
    for (int pass = 0; pass < 2; pass++) {
        const char* Abase = (pass == 1) ? (buf + 32768) : buf;
        for (int kb = 0; kb < 8; kb++) {
            bf8_t a[4], b[2];
            #pragma unroll
            for (int mi = 0; mi < 4; mi++) {
                int row = mi * 16 + cb;
                int byte = (row * 512 + kb * 64 + kg * 16) ^ ((row & 7) << 4);
                a[mi] = *(const bf8_t*)(Abase + byte);
            }
            #pragma unroll
            for (int ni = 0; ni < 2; ni++) {
                int nb = wv * 2 + ni;
                b[ni] = *(const bf8_t*)&g1h[(size_t)(nb * 8 + kb) * 512 + lane * 8];
            }
            #pragma unroll
            for (int mi = 0; mi < 4; mi++)
                #pragma unroll
                for (int ni = 0; ni < 2; ni++)
                    acc[mi][ni] = __builtin_amdgcn_mfma_f32_16x16x32_bf16(a[mi], b[ni], acc[mi][ni], 0, 0, 0);
        }
    }
    __syncthreads();

    {
        float* G1 = (float*)buf;
        float bias1[2];
        bias1[0] = gb1[wv * 32 + cb];
        bias1[1] = gb1[wv * 32 + 16 + cb];
        #pragma unroll
        for (int mi = 0; mi < 4; mi++) {
            #pragma unroll
            for (int ni = 0; ni < 2; ni++) {
                int colv = wv * 32 + ni * 16 + cb;
                #pragma unroll
                for (int j = 0; j < 4; j++) {
                    int row = mi * 16 + kg * 4 + j;
                    G1[row * PHD + colv] = relu_f(acc[mi][ni][j] + bias1[ni]);
                }
            }
        }
    }
    __syncthreads();

    {
        const float* G1 = (const float*)buf;
        float2 wv2 = *(const float2*)&gw2[lane * 2];
        float b2v = gb2[0];
        for (int rr = 0; rr < 16; rr++) {
            int row = wv * 16 + rr;
            long grow = row0 + row;
            if (grow >= N_NODES) break;
            float2 t2 = *(const float2*)&G1[row * PHD + lane * 2];
            float p = t2.x * wv2.x + t2.y * wv2.y;
            #pragma unroll
            for (int off = 32; off > 0; off >>= 1) p += __shfl_xor(p, off, 64);
            if (lane == 0) gate[grow] = p + b2v;
        }
    }
}

// ---------------- graph offsets ----------------
__global__ void goff_kernel(const int* __restrict__ batch, int* __restrict__ goff, int n)
{
    int t = threadIdx.x;
    if (t > NG) return;
    int lo = 0, hi = n;
    while (lo < hi) {
        int mid = (lo + hi) >> 1;
        if (batch[mid] < t) lo = mid + 1; else hi = mid;
    }
    goff[t] = lo;
}

// ---------------- softmax-weighted pooling (4 blocks per graph, atomic accumulate) ----------------
__global__ __launch_bounds__(256) void pool_kernel(
    const float* __restrict__ h, const float* __restrict__ gate,
    const int* __restrict__ goff, float* __restrict__ pooled)
{
    __shared__ float red[256];
    __shared__ float m_sh, s_sh;
    int g = blockIdx.x >> 2, q = blockIdx.x & 3;
    int tid = threadIdx.x;
    int beg = goff[g], end = goff[g + 1];
    if (beg >= end) return;   // pooled pre-zeroed

    float lm = -3.4e38f;
    for (int i = beg + tid; i < end; i += 256) lm = fmaxf(lm, gate[i]);
    red[tid] = lm; __syncthreads();
    for (int off = 128; off > 0; off >>= 1) {
        if (tid < off) red[tid] = fmaxf(red[tid], red[tid + off]);
        __syncthreads();
    }
    if (tid == 0) m_sh = red[0];
    __syncthreads();
    float m = m_sh;

    float ls = 0.0f;
    for (int i = beg + tid; i < end; i += 256) ls += expf(gate[i] - m);
    __syncthreads();
    red[tid] = ls; __syncthreads();
    for (int off = 128; off > 0; off >>= 1) {
        if (tid < off) red[tid] += red[tid + off];
        __syncthreads();
    }
    if (tid == 0) s_sh = red[0];
    __syncthreads();
    float inv_s = 1.0f / s_sh;

    float acc = 0.0f;
    for (int i = beg + q; i < end; i += 4) {
        float a = expf(gate[i] - m);
        acc += a * h[(size_t)i * HD + tid];
    }
    atomicAdd(&pooled[(size_t)g * HD + tid], acc * inv_s);
}

// ---------------- classifier ----------------
__global__ __launch_bounds__(128) void cls_kernel(
    const float* __restrict__ pooled, const float* __restrict__ gf,
    const float* __restrict__ w1, const float* __restrict__ b1,
    const float* __restrict__ w2, const float* __restrict__ b2,
    float* __restrict__ out)
{
    __shared__ float r0[128], r1[128];
    int g = blockIdx.x, c = threadIdx.x;
    float acc = b1[c];
    const float* pr = pooled + (size_t)g * HD;
    for (int k = 0; k < HD; k++) acc += pr[k] * w1[k * PHD + c];
    const float* gr = gf + g * GFD;
    for (int k = 0; k < GFD; k++) acc += gr[k] * w1[(HD + k) * PHD + c];
    float t = relu_f(acc);
    r0[c] = t * w2[c * 2 + 0];
    r1[c] = t * w2[c * 2 + 1];
    __syncthreads();
    for (int off = 64; off > 0; off >>= 1) {
        if (c < off) { r0[c] += r0[c + off]; r1[c] += r1[c + off]; }
        __syncthreads();
    }
    if (c == 0) {
        out[g * 2 + 0] = r0[0] + b2[0];
        out[g * 2 + 1] = r1[0] + b2[1];
    }
}

extern "C" void kernel_launch(void* const* d_in, const int* in_sizes, int n_in,
                              void* d_out, int out_size, void* d_ws, size_t ws_size,
                              hipStream_t stream)
{
    const float* x    = (const float*)d_in[0];
    const int*   ei   = (const int*)d_in[1];
    const int*   bat  = (const int*)d_in[2];
    const float* gf   = (const float*)d_in[3];
    const float* emb  = (const float*)d_in[4];
    const float* l0w1 = (const float*)d_in[5];
    const float* l0b1 = (const float*)d_in[6];
    const float* l0w2 = (const float*)d_in[7];
    const float* l0b2 = (const float*)d_in[8];
    const float* ln0g = (const float*)d_in[9];
    const float* ln0b = (const float*)d_in[10];
    const float* l1w1 = (const float*)d_in[11];
    const float* l1b1 = (const float*)d_in[12];
    const float* l1w2 = (const float*)d_in[13];
    const float* l1b2 = (const float*)d_in[14];
    const float* ln1g = (const float*)d_in[15];
    const float* ln1b = (const float*)d_in[16];
    const float* gw1  = (const float*)d_in[17];
    const float* gb1  = (const float*)d_in[18];
    const float* gw2  = (const float*)d_in[19];
    const float* gb2  = (const float*)d_in[20];
    const float* cw1  = (const float*)d_in[21];
    const float* cb1  = (const float*)d_in[22];
    const float* cw2  = (const float*)d_in[23];
    const float* cb2  = (const float*)d_in[24];

    char* ws = (char*)d_ws;
    size_t off = 0;
    auto alloc = [&](size_t bytes) {
        void* p = ws + off;
        off += (bytes + 255) & ~(size_t)255;
        return p;
    };
    float* h      = (float*)alloc((size_t)N_NODES * HD * 4);
    unsigned short* h16a = (unsigned short*)alloc((size_t)N_NODES * HD * 2);
    unsigned short* h16b = (unsigned short*)alloc((size_t)N_NODES * HD * 2);
    float* gate   = (float*)alloc((size_t)N_NODES * 4);
    int*   cnt    = (int*)alloc((size_t)N_NODES * 4);
    int*   col    = (int*)alloc((size_t)N_NODES * SLOT * 4);
    int*   goff   = (int*)alloc((NG + 1) * 4);
    float* pooled = (float*)alloc((size_t)NG * HD * 4);
    short* p_l0w1h = (short*)alloc((size_t)HD * HD * 2);
    short* p_l0w2h = (short*)alloc((size_t)HD * HD * 2);
    short* p_l1w1h = (short*)alloc((size_t)HD * HD * 2);
    short* p_l1w2h = (short*)alloc((size_t)HD * HD * 2);
    short* p_gw1h  = (short*)alloc((size_t)HD * PHD * 2);

    const int* src = ei;
    const int* dst = ei + N_EDGES;

    build_h_kernel<<<N_NODES, 256, 0, stream>>>(x, emb, h, h16a);

    // slot-bucketed CSR: one atomic pass, no count/scan
    hipMemsetAsync(cnt, 0, (size_t)N_NODES * 4, stream);
    fill_slots_kernel<<<(N_EDGES + 255) / 256, 256, 0, stream>>>(src, dst, cnt, col, N_EDGES);

    pack_all_kernel<<<144, 256, 0, stream>>>(l0w1, l0w2, l1w1, l1w2, gw1,
                                             p_l0w1h, p_l0w2h, p_l1w1h, p_l1w2h, p_gw1h);

    const int layer_grid = N_NODES / 32;   // 3125 exact

    // GIN block 0: gather from h16a, write h16b
    gin_layer_kernel<<<layer_grid, 256, 0, stream>>>(h, h16a, h16b, cnt, col,
                                                     p_l0w1h, l0b1, p_l0w2h, l0b2, ln0g, ln0b);
    // GIN block 1: gather from h16b, write h16a
    gin_layer_kernel<<<layer_grid, 256, 0, stream>>>(h, h16b, h16a, cnt, col,
                                                     p_l1w1h, l1b1, p_l1w2h, l1b2, ln1g, ln1b);

    gate_mfma_kernel<<<(N_NODES + 63) / 64, 256, 0, stream>>>(h, p_gw1h, gb1, gw2, gb2, gate);
    goff_kernel<<<1, 256, 0, stream>>>(bat, goff, N_NODES);
    hipMemsetAsync(pooled, 0, (size_t)NG * HD * 4, stream);
    pool_kernel<<<NG * 4, 256, 0, stream>>>(h, gate, goff, pooled);
    cls_kernel<<<NG, 128, 0, stream>>>(pooled, gf, cw1, cb1, cw2, cb2, (float*)d_out);
}